// Round 5
// baseline (174.916 us; speedup 1.0000x reference)
//
#include <hip/hip_runtime.h>
#include <math.h>

// ---------------------------------------------------------------------------
// Cosine_PredictingModule v5 (= v4 with the edge grid-size bug fixed).
//   cat@W1 = heads@W1a + tails@W1b + cos*W1[128]  (per-node precompute).
//   Tables: hn = fp8 e4m3 normalized row (64B/node), P = bf16 h@W1half(+b1)
//   (128B/node). cos denom folded (≈1 to 1e-7); b1 folded into customer P.
//   K0 prep_w1: W1 -> bf16 MFMA B-fragment order.
//   K1 node_fused: h fp32 loaded DIRECTLY in MFMA A-layout (no A LDS pass),
//      norm via 2 shuffles, fp8 row from regs, single barrier (P transpose).
//   K2 edge_mlp: one-shot, 16 edges/wave, 4 lanes/edge; 64 edges/block ->
//      grid = ceil(nE/64)  [v4 bug: launched 3920 blocks, needed 15625].
// ---------------------------------------------------------------------------

typedef __attribute__((ext_vector_type(8))) short bf16x8;
typedef __attribute__((ext_vector_type(4))) float f32x4;
typedef __attribute__((ext_vector_type(2))) float float2_t;
typedef __attribute__((ext_vector_type(8))) unsigned short ushort8_t;
typedef __attribute__((ext_vector_type(4))) float float4_t;
typedef __attribute__((ext_vector_type(4))) unsigned int uint4_t;
typedef __attribute__((ext_vector_type(2))) unsigned int uint2_t;

#define P_STRIDE 72   // acc-transpose LDS stride (ushorts)

__device__ __forceinline__ float bf2f(unsigned short u) {
    return __uint_as_float(((unsigned int)u) << 16);
}
__device__ __forceinline__ unsigned short f2bf(float f) {
    unsigned int x = __float_as_uint(f);
    return (unsigned short)((x + 0x7fffu + ((x >> 16) & 1u)) >> 16);
}

// K0: W1frag[half][nt][ks][lane][j] =
//   bf16(W1[half*64 + ks*32 + (lane>>4)*8 + j][nt*16 + (lane&15)])
__global__ __launch_bounds__(256) void prep_w1(
    const float* __restrict__ W1, unsigned short* __restrict__ frag)
{
    int idx = blockIdx.x * 256 + threadIdx.x;
    if (idx >= 2 * 4 * 2 * 64 * 8) return;
    int j    = idx & 7;
    int lane = (idx >> 3) & 63;
    int ks   = (idx >> 9) & 1;
    int nt   = (idx >> 10) & 3;
    int half = (idx >> 12) & 1;
    int k   = ks * 32 + (lane >> 4) * 8 + j;
    int col = nt * 16 + (lane & 15);
    frag[idx] = f2bf(W1[(half * 64 + k) * 64 + col]);
}

// K1: 64 nodes/block, 4 waves x 16 nodes. One barrier.
__global__ __launch_bounds__(256) void node_fused(
    const float* __restrict__ hc, const float* __restrict__ hp,
    const unsigned short* __restrict__ w1frag, const float* __restrict__ b1,
    unsigned int* __restrict__ hnc, unsigned int* __restrict__ hnp,
    unsigned short* __restrict__ pcb, unsigned short* __restrict__ ppb,
    int nC, int nP, int blocksC)
{
    __shared__ unsigned short tile2[64 * P_STRIDE];  // 9.2 KB

    int b = blockIdx.x;
    const float* h; unsigned int* hn; unsigned short* pj; int n, half;
    if (b < blocksC) { h = hc; hn = hnc; pj = pcb; n = nC; half = 0; }
    else { b -= blocksC; h = hp; hn = hnp; pj = ppb; n = nP; half = 1; }

    int node0 = b * 64;
    int nloc  = min(64, n - node0);
    int t     = threadIdx.x;
    int wave  = t >> 6, lane = t & 63;
    int m = lane & 15, quad = lane >> 4;

    if (wave * 16 < nloc) {
        int row = node0 + wave * 16 + m;   // nloc is a multiple of 16 here
        // Load h directly in MFMA A-fragment layout: 16 dims/lane.
        float4_t f[2][2];
#pragma unroll
        for (int ks = 0; ks < 2; ks++) {
            const float* srcp = h + (long)row * 64 + ks * 32 + quad * 8;
            f[ks][0] = *reinterpret_cast<const float4_t*>(srcp);
            f[ks][1] = *reinterpret_cast<const float4_t*>(srcp + 4);
        }

        // Row norm: this row's 64 dims live in lanes {m, m+16, m+32, m+48}.
        float ss = 0.f;
#pragma unroll
        for (int ks = 0; ks < 2; ks++)
#pragma unroll
            for (int i = 0; i < 2; i++)
#pragma unroll
                for (int j = 0; j < 4; j++) ss += f[ks][i][j] * f[ks][i][j];
        ss += __shfl_xor(ss, 16);
        ss += __shfl_xor(ss, 32);
        float inv = 1.f / fmaxf(sqrtf(ss), 1e-12f);

        // fp8 e4m3 normalized: lane covers dims [ks*32+quad*8, +8) -> 2x8B.
#pragma unroll
        for (int ks = 0; ks < 2; ks++) {
            uint2_t u8;
#pragma unroll
            for (int i = 0; i < 2; i++) {
                unsigned int d = __builtin_amdgcn_cvt_pk_fp8_f32(
                    f[ks][i][0] * inv, f[ks][i][1] * inv, 0, false);
                d = __builtin_amdgcn_cvt_pk_fp8_f32(
                    f[ks][i][2] * inv, f[ks][i][3] * inv, d, true);
                u8[i] = d;
            }
            *reinterpret_cast<uint2_t*>(
                reinterpret_cast<char*>(hn) + (long)row * 64 + ks * 32 + quad * 8) = u8;
        }

        // A fragments (bf16) from registers.
        bf16x8 a[2];
#pragma unroll
        for (int ks = 0; ks < 2; ks++)
#pragma unroll
            for (int i = 0; i < 8; i++)
                a[ks][i] = (short)f2bf(f[ks][i >> 2][i & 3]);

        f32x4 acc[4];
#pragma unroll
        for (int nt = 0; nt < 4; nt++) acc[nt] = (f32x4){0.f, 0.f, 0.f, 0.f};
#pragma unroll
        for (int nt = 0; nt < 4; nt++)
#pragma unroll
            for (int ks = 0; ks < 2; ks++) {
                bf16x8 bf = *reinterpret_cast<const bf16x8*>(
                    &w1frag[(((half * 4 + nt) * 2 + ks) * 64 + lane) * 8]);
                acc[nt] = __builtin_amdgcn_mfma_f32_16x16x32_bf16(
                    a[ks], bf, acc[nt], 0, 0, 0);
            }
        if (half == 0) {     // fold b1 into customer-side P
#pragma unroll
            for (int nt = 0; nt < 4; nt++) {
                float bb = b1[nt * 16 + m];
#pragma unroll
                for (int r = 0; r < 4; r++) acc[nt][r] += bb;
            }
        }
        // C/D: col = lane&15, row = quad*4 + reg -> LDS transpose
#pragma unroll
        for (int nt = 0; nt < 4; nt++)
#pragma unroll
            for (int r = 0; r < 4; r++)
                tile2[(wave * 16 + quad * 4 + r) * P_STRIDE + nt * 16 + m]
                    = f2bf(acc[nt][r]);
    }
    __syncthreads();

    int nl = t >> 2, q = t & 3;
    if (nl < nloc) {   // coalesced 16B P stores
        ushort8_t p0 = *reinterpret_cast<ushort8_t*>(&tile2[nl * P_STRIDE + q * 16]);
        ushort8_t p1 = *reinterpret_cast<ushort8_t*>(&tile2[nl * P_STRIDE + q * 16 + 8]);
        unsigned short* dstp = pj + (long)(node0 + nl) * 64 + q * 16;
        *reinterpret_cast<ushort8_t*>(dstp)     = p0;
        *reinterpret_cast<ushort8_t*>(dstp + 8) = p1;
    }
}

// K2: one-shot, 4 lanes/edge, 16 edges/wave (64 edges per 256-thread block).
__global__ __launch_bounds__(256) void edge_mlp(
    const unsigned int* __restrict__ hnc, const unsigned int* __restrict__ hnp,
    const unsigned short* __restrict__ pc, const unsigned short* __restrict__ pp,
    const int* __restrict__ src, const int* __restrict__ dst,
    const float* __restrict__ W1, const float* __restrict__ W2,
    const float* __restrict__ b2, float* __restrict__ out, int nE)
{
    int lane = threadIdx.x & 63;
    int sub  = lane >> 2;      // edge within wave (0..15)
    int g    = lane & 3;       // lane within edge group
    int d0   = g * 16;         // dims [d0, d0+16)
    int e    = ((blockIdx.x * 256 + threadIdx.x) >> 6) * 16 + sub;
    bool valid = e < nE;
    int s = valid ? src[e] : 0;
    int t = valid ? dst[e] : 0;

    // Gathers first (longest latency).
    uint4_t hs = *reinterpret_cast<const uint4_t*>(hnc + (long)s * 16 + g * 4);
    uint4_t ht = *reinterpret_cast<const uint4_t*>(hnp + (long)t * 16 + g * 4);
    ushort8_t ps0 = *reinterpret_cast<const ushort8_t*>(pc + (long)s * 64 + d0);
    ushort8_t ps1 = *reinterpret_cast<const ushort8_t*>(pc + (long)s * 64 + d0 + 8);
    ushort8_t pt0 = *reinterpret_cast<const ushort8_t*>(pp + (long)t * 64 + d0);
    ushort8_t pt1 = *reinterpret_cast<const ushort8_t*>(pp + (long)t * 64 + d0 + 8);

    // L1-hot parameter loads.
    float4_t w1v[4], w2v[4];
#pragma unroll
    for (int i = 0; i < 4; i++) {
        w1v[i] = *reinterpret_cast<const float4_t*>(W1 + 128 * 64 + d0 + i * 4);
        w2v[i] = *reinterpret_cast<const float4_t*>(W2 + d0 + i * 4);
    }
    float b2v = b2[0];

    // fp8 -> f32 and dot (16 dims/lane).
    float dot = 0.f;
#pragma unroll
    for (int w = 0; w < 4; w++) {
        float2_t alo = __builtin_amdgcn_cvt_pk_f32_fp8((int)hs[w], false);
        float2_t ahi = __builtin_amdgcn_cvt_pk_f32_fp8((int)hs[w], true);
        float2_t blo = __builtin_amdgcn_cvt_pk_f32_fp8((int)ht[w], false);
        float2_t bhi = __builtin_amdgcn_cvt_pk_f32_fp8((int)ht[w], true);
        dot += alo[0] * blo[0] + alo[1] * blo[1] + ahi[0] * bhi[0] + ahi[1] * bhi[1];
    }
    dot += __shfl_xor(dot, 1);
    dot += __shfl_xor(dot, 2);
    float cosv = dot;                    // denom folded (≈1 to 1e-7)

    float p = 0.f;
#pragma unroll
    for (int i = 0; i < 16; i++) {
        float pcv = bf2f(i < 8 ? ps0[i] : ps1[i - 8]);
        float ppv = bf2f(i < 8 ? pt0[i] : pt1[i - 8]);
        float x = pcv + ppv + cosv * w1v[i >> 2][i & 3];   // b1 folded into Pc
        x = fmaxf(x, 0.f);
        p += x * w2v[i >> 2][i & 3];
    }
    p += __shfl_xor(p, 1);
    p += __shfl_xor(p, 2);

    if (valid && g == 0)
        out[e] = 1.f / (1.f + expf(-(p + b2v)));
}

extern "C" void kernel_launch(void* const* d_in, const int* in_sizes, int n_in,
                              void* d_out, int out_size, void* d_ws, size_t ws_size,
                              hipStream_t stream) {
    const float* h_c = (const float*)d_in[0];
    const float* h_p = (const float*)d_in[1];
    const int*   src = (const int*)d_in[2];
    const int*   dst = (const int*)d_in[3];
    const float* W1  = (const float*)d_in[4];
    const float* b1  = (const float*)d_in[5];
    const float* W2  = (const float*)d_in[6];
    const float* b2  = (const float*)d_in[7];
    float* out = (float*)d_out;

    int nC = in_sizes[0] / 64;
    int nP = in_sizes[1] / 64;
    int nE = in_sizes[2];

    char* ws = (char*)d_ws;
    size_t off = 0;
    auto carve = [&](size_t bytes) {
        void* p = ws + off;
        off = (off + bytes + 255) & ~(size_t)255;
        return p;
    };
    unsigned int*   hnc = (unsigned int*)carve((size_t)nC * 64);        // fp8
    unsigned int*   hnp = (unsigned int*)carve((size_t)nP * 64);        // fp8
    unsigned short* pcb = (unsigned short*)carve((size_t)nC * 64 * 2);  // bf16
    unsigned short* ppb = (unsigned short*)carve((size_t)nP * 64 * 2);  // bf16
    unsigned short* w1f = (unsigned short*)carve((size_t)16384 * 2);

    prep_w1<<<64, 256, 0, stream>>>(W1, w1f);

    int blocksC = (nC + 63) / 64, blocksP = (nP + 63) / 64;
    node_fused<<<blocksC + blocksP, 256, 0, stream>>>(
        h_c, h_p, w1f, b1, hnc, hnp, pcb, ppb, nC, nP, blocksC);

    // 64 edges per block.
    edge_mlp<<<(nE + 63) / 64, 256, 0, stream>>>(
        hnc, hnp, pcb, ppb, src, dst, W1, W2, b2, out, nE);
}

// Round 6
// 148.312 us; speedup vs baseline: 1.1794x; 1.1794x over previous
//
#include <hip/hip_runtime.h>
#include <math.h>

// ---------------------------------------------------------------------------
// Cosine_PredictingModule v6.
//   cat@W1 = heads@W1a + tails@W1b + cos*W1[128]  (per-node precompute).
//   NEW: single-cache-line node record (128 B):
//        bytes [0,64)   = fp8 e4m3 normalized row hn (cosine path)
//        bytes [64,128) = fp8 e4m3 P = h@W1half (+b1 for customers)
//   -> each edge gathers exactly 2 cache lines (was 3-4 across 2 regions).
//   cos denom folded (≈1 to 1e-7); b1 folded into customer P.
//   K0 prep_w1: W1 -> bf16 MFMA B-fragment order.
//   K1 node_fused: h fp32 in MFMA A-layout, norm via 2 shuffles, fp8 hn from
//      regs, P via MFMA -> LDS transpose -> fp8; writes the packed record.
//   K2 edge_mlp: one-shot, 4 lanes/edge, 16 edges/wave; per lane 4x16B
//      gather loads (2 per node record).
// ---------------------------------------------------------------------------

typedef __attribute__((ext_vector_type(8))) short bf16x8;
typedef __attribute__((ext_vector_type(4))) float f32x4;
typedef __attribute__((ext_vector_type(2))) float float2_t;
typedef __attribute__((ext_vector_type(8))) unsigned short ushort8_t;
typedef __attribute__((ext_vector_type(4))) float float4_t;
typedef __attribute__((ext_vector_type(4))) unsigned int uint4_t;
typedef __attribute__((ext_vector_type(2))) unsigned int uint2_t;

#define P_STRIDE 72   // acc-transpose LDS stride (ushorts)

__device__ __forceinline__ float bf2f(unsigned short u) {
    return __uint_as_float(((unsigned int)u) << 16);
}
__device__ __forceinline__ unsigned short f2bf(float f) {
    unsigned int x = __float_as_uint(f);
    return (unsigned short)((x + 0x7fffu + ((x >> 16) & 1u)) >> 16);
}

// K0: W1frag[half][nt][ks][lane][j] =
//   bf16(W1[half*64 + ks*32 + (lane>>4)*8 + j][nt*16 + (lane&15)])
__global__ __launch_bounds__(256) void prep_w1(
    const float* __restrict__ W1, unsigned short* __restrict__ frag)
{
    int idx = blockIdx.x * 256 + threadIdx.x;
    if (idx >= 2 * 4 * 2 * 64 * 8) return;
    int j    = idx & 7;
    int lane = (idx >> 3) & 63;
    int ks   = (idx >> 9) & 1;
    int nt   = (idx >> 10) & 3;
    int half = (idx >> 12) & 1;
    int k   = ks * 32 + (lane >> 4) * 8 + j;
    int col = nt * 16 + (lane & 15);
    frag[idx] = f2bf(W1[(half * 64 + k) * 64 + col]);
}

// K1: 64 nodes/block, 4 waves x 16 nodes. One barrier.
// rec: 128 B per node = [fp8 hn x64 | fp8 P x64].
__global__ __launch_bounds__(256) void node_fused(
    const float* __restrict__ hc, const float* __restrict__ hp,
    const unsigned short* __restrict__ w1frag, const float* __restrict__ b1,
    unsigned char* __restrict__ recC, unsigned char* __restrict__ recP,
    int nC, int nP, int blocksC)
{
    __shared__ unsigned short tile2[64 * P_STRIDE];  // 9.2 KB

    int b = blockIdx.x;
    const float* h; unsigned char* rec; int n, half;
    if (b < blocksC) { h = hc; rec = recC; n = nC; half = 0; }
    else { b -= blocksC; h = hp; rec = recP; n = nP; half = 1; }

    int node0 = b * 64;
    int nloc  = min(64, n - node0);
    int t     = threadIdx.x;
    int wave  = t >> 6, lane = t & 63;
    int m = lane & 15, quad = lane >> 4;

    if (wave * 16 < nloc) {
        int row = node0 + wave * 16 + m;   // nloc is a multiple of 16 here
        // Load h directly in MFMA A-fragment layout: 16 dims/lane.
        float4_t f[2][2];
#pragma unroll
        for (int ks = 0; ks < 2; ks++) {
            const float* srcp = h + (long)row * 64 + ks * 32 + quad * 8;
            f[ks][0] = *reinterpret_cast<const float4_t*>(srcp);
            f[ks][1] = *reinterpret_cast<const float4_t*>(srcp + 4);
        }

        // Row norm: this row's 64 dims live in lanes {m, m+16, m+32, m+48}.
        float ss = 0.f;
#pragma unroll
        for (int ks = 0; ks < 2; ks++)
#pragma unroll
            for (int i = 0; i < 2; i++)
#pragma unroll
                for (int j = 0; j < 4; j++) ss += f[ks][i][j] * f[ks][i][j];
        ss += __shfl_xor(ss, 16);
        ss += __shfl_xor(ss, 32);
        float inv = 1.f / fmaxf(sqrtf(ss), 1e-12f);

        // fp8 e4m3 normalized hn -> record bytes [ks*32+quad*8, +8).
#pragma unroll
        for (int ks = 0; ks < 2; ks++) {
            uint2_t u8;
#pragma unroll
            for (int i = 0; i < 2; i++) {
                unsigned int d = __builtin_amdgcn_cvt_pk_fp8_f32(
                    f[ks][i][0] * inv, f[ks][i][1] * inv, 0, false);
                d = __builtin_amdgcn_cvt_pk_fp8_f32(
                    f[ks][i][2] * inv, f[ks][i][3] * inv, d, true);
                u8[i] = d;
            }
            *reinterpret_cast<uint2_t*>(rec + (long)row * 128 + ks * 32 + quad * 8) = u8;
        }

        // A fragments (bf16) from registers.
        bf16x8 a[2];
#pragma unroll
        for (int ks = 0; ks < 2; ks++)
#pragma unroll
            for (int i = 0; i < 8; i++)
                a[ks][i] = (short)f2bf(f[ks][i >> 2][i & 3]);

        f32x4 acc[4];
#pragma unroll
        for (int nt = 0; nt < 4; nt++) acc[nt] = (f32x4){0.f, 0.f, 0.f, 0.f};
#pragma unroll
        for (int nt = 0; nt < 4; nt++)
#pragma unroll
            for (int ks = 0; ks < 2; ks++) {
                bf16x8 bf = *reinterpret_cast<const bf16x8*>(
                    &w1frag[(((half * 4 + nt) * 2 + ks) * 64 + lane) * 8]);
                acc[nt] = __builtin_amdgcn_mfma_f32_16x16x32_bf16(
                    a[ks], bf, acc[nt], 0, 0, 0);
            }
        if (half == 0) {     // fold b1 into customer-side P
#pragma unroll
            for (int nt = 0; nt < 4; nt++) {
                float bb = b1[nt * 16 + m];
#pragma unroll
                for (int r = 0; r < 4; r++) acc[nt][r] += bb;
            }
        }
        // C/D: col = lane&15, row = quad*4 + reg -> LDS transpose
#pragma unroll
        for (int nt = 0; nt < 4; nt++)
#pragma unroll
            for (int r = 0; r < 4; r++)
                tile2[(wave * 16 + quad * 4 + r) * P_STRIDE + nt * 16 + m]
                    = f2bf(acc[nt][r]);
    }
    __syncthreads();

    int nl = t >> 2, q = t & 3;
    if (nl < nloc) {   // P (fp8) -> record bytes [64 + q*16, +16), 16B store
        ushort8_t p0 = *reinterpret_cast<ushort8_t*>(&tile2[nl * P_STRIDE + q * 16]);
        ushort8_t p1 = *reinterpret_cast<ushort8_t*>(&tile2[nl * P_STRIDE + q * 16 + 8]);
        float v[16];
#pragma unroll
        for (int i = 0; i < 8; i++) { v[i] = bf2f(p0[i]); v[i + 8] = bf2f(p1[i]); }
        uint4_t u;
#pragma unroll
        for (int i = 0; i < 4; i++) {
            unsigned int d = __builtin_amdgcn_cvt_pk_fp8_f32(
                v[i * 4 + 0], v[i * 4 + 1], 0, false);
            d = __builtin_amdgcn_cvt_pk_fp8_f32(
                v[i * 4 + 2], v[i * 4 + 3], d, true);
            u[i] = d;
        }
        *reinterpret_cast<uint4_t*>(rec + (long)(node0 + nl) * 128 + 64 + q * 16) = u;
    }
}

// K2: one-shot, 4 lanes/edge, 16 edges/wave; 2 lines gathered per edge.
__global__ __launch_bounds__(256) void edge_mlp(
    const unsigned char* __restrict__ recC, const unsigned char* __restrict__ recP,
    const int* __restrict__ src, const int* __restrict__ dst,
    const float* __restrict__ W1, const float* __restrict__ W2,
    const float* __restrict__ b2, float* __restrict__ out, int nE)
{
    int lane = threadIdx.x & 63;
    int sub  = lane >> 2;      // edge within wave (0..15)
    int g    = lane & 3;       // lane within edge group
    int d0   = g * 16;         // dims [d0, d0+16)
    int e    = ((blockIdx.x * 256 + threadIdx.x) >> 6) * 16 + sub;
    bool valid = e < nE;
    int s = valid ? src[e] : 0;
    int t = valid ? dst[e] : 0;

    // Gathers: 2x16B per node record (hn half + P half).
    const unsigned char* rs = recC + (long)s * 128;
    const unsigned char* rt = recP + (long)t * 128;
    uint4_t hs = *reinterpret_cast<const uint4_t*>(rs + d0);
    uint4_t ht = *reinterpret_cast<const uint4_t*>(rt + d0);
    uint4_t ps = *reinterpret_cast<const uint4_t*>(rs + 64 + d0);
    uint4_t pt = *reinterpret_cast<const uint4_t*>(rt + 64 + d0);

    // L1-hot parameter loads.
    float4_t w1v[4], w2v[4];
#pragma unroll
    for (int i = 0; i < 4; i++) {
        w1v[i] = *reinterpret_cast<const float4_t*>(W1 + 128 * 64 + d0 + i * 4);
        w2v[i] = *reinterpret_cast<const float4_t*>(W2 + d0 + i * 4);
    }
    float b2v = b2[0];

    // cosine partial dot (16 dims/lane).
    float dot = 0.f;
#pragma unroll
    for (int w = 0; w < 4; w++) {
        float2_t alo = __builtin_amdgcn_cvt_pk_f32_fp8((int)hs[w], false);
        float2_t ahi = __builtin_amdgcn_cvt_pk_f32_fp8((int)hs[w], true);
        float2_t blo = __builtin_amdgcn_cvt_pk_f32_fp8((int)ht[w], false);
        float2_t bhi = __builtin_amdgcn_cvt_pk_f32_fp8((int)ht[w], true);
        dot += alo[0] * blo[0] + alo[1] * blo[1] + ahi[0] * bhi[0] + ahi[1] * bhi[1];
    }
    dot += __shfl_xor(dot, 1);
    dot += __shfl_xor(dot, 2);
    float cosv = dot;                    // denom folded (≈1 to 1e-7)

    // MLP partial (16 dims/lane): x = relu(Pc+Pp+cos*w1l), p += x*w2.
    float p = 0.f;
#pragma unroll
    for (int w = 0; w < 4; w++) {
        float2_t clo = __builtin_amdgcn_cvt_pk_f32_fp8((int)ps[w], false);
        float2_t chi = __builtin_amdgcn_cvt_pk_f32_fp8((int)ps[w], true);
        float2_t dlo = __builtin_amdgcn_cvt_pk_f32_fp8((int)pt[w], false);
        float2_t dhi = __builtin_amdgcn_cvt_pk_f32_fp8((int)pt[w], true);
        float pcv[4] = {clo[0], clo[1], chi[0], chi[1]};
        float ppv[4] = {dlo[0], dlo[1], dhi[0], dhi[1]};
#pragma unroll
        for (int j = 0; j < 4; j++) {
            float x = pcv[j] + ppv[j] + cosv * w1v[w][j];   // b1 folded into Pc
            x = fmaxf(x, 0.f);
            p += x * w2v[w][j];
        }
    }
    p += __shfl_xor(p, 1);
    p += __shfl_xor(p, 2);

    if (valid && g == 0)
        out[e] = 1.f / (1.f + expf(-(p + b2v)));
}

extern "C" void kernel_launch(void* const* d_in, const int* in_sizes, int n_in,
                              void* d_out, int out_size, void* d_ws, size_t ws_size,
                              hipStream_t stream) {
    const float* h_c = (const float*)d_in[0];
    const float* h_p = (const float*)d_in[1];
    const int*   src = (const int*)d_in[2];
    const int*   dst = (const int*)d_in[3];
    const float* W1  = (const float*)d_in[4];
    const float* b1  = (const float*)d_in[5];
    const float* W2  = (const float*)d_in[6];
    const float* b2  = (const float*)d_in[7];
    float* out = (float*)d_out;

    int nC = in_sizes[0] / 64;
    int nP = in_sizes[1] / 64;
    int nE = in_sizes[2];

    char* ws = (char*)d_ws;
    size_t off = 0;
    auto carve = [&](size_t bytes) {
        void* p = ws + off;
        off = (off + bytes + 255) & ~(size_t)255;
        return p;
    };
    unsigned char* recC = (unsigned char*)carve((size_t)nC * 128);
    unsigned char* recP = (unsigned char*)carve((size_t)nP * 128);
    unsigned short* w1f = (unsigned short*)carve((size_t)16384 * 2);

    prep_w1<<<64, 256, 0, stream>>>(W1, w1f);

    int blocksC = (nC + 63) / 64, blocksP = (nP + 63) / 64;
    node_fused<<<blocksC + blocksP, 256, 0, stream>>>(
        h_c, h_p, w1f, b1, recC, recP, nC, nP, blocksC);

    // 64 edges per block.
    edge_mlp<<<(nE + 63) / 64, 256, 0, stream>>>(
        recC, recP, src, dst, W1, W2, b2, out, nE);
}